// Round 5
// baseline (404.015 us; speedup 1.0000x reference)
//
#include <hip/hip_runtime.h>
#include <stdint.h>

#define Bdim 32
#define Tdim 12
#define Vdim 1024
#define Edim 64
#define Gdim 32
#define BT   384   // B*T

typedef __attribute__((ext_vector_type(8))) short bf16x8;
typedef __attribute__((ext_vector_type(4))) float f32x4;

__device__ __forceinline__ ushort f2bf(float f) {
    uint u = __float_as_uint(f);
    u += 0x7fffu + ((u >> 16) & 1u);      // RNE
    return (ushort)(u >> 16);
}
__device__ __forceinline__ uint pk2(float a, float b) {
    return (uint)f2bf(a) | ((uint)f2bf(b) << 16);
}

// ---------------------------------------------------------------------------
// K1a: Xbf[e][bt][i] (bf16) = inputs[bt][i][e] (f32)
// ---------------------------------------------------------------------------
__global__ __launch_bounds__(256) void k_xpose(const float* __restrict__ in,
                                               ushort* __restrict__ Xbf) {
    __shared__ float tile[64][68];
    const int bt = blockIdx.x >> 4;
    const int i0 = (blockIdx.x & 15) << 6;
    const int r  = threadIdx.x >> 2;     // i-local on load, e on store
    const int q  = threadIdx.x & 3;
    const float* src = in + ((size_t)(bt * Vdim) + i0 + r) * Edim + q * 16;
#pragma unroll
    for (int k = 0; k < 4; ++k)
        *(float4*)&tile[r][q * 16 + 4 * k] = *(const float4*)(src + 4 * k);
    __syncthreads();
    const int e  = r;
    const int ib = q * 16;
    uint4 s0, s1;
    s0.x = pk2(tile[ib + 0][e],  tile[ib + 1][e]);
    s0.y = pk2(tile[ib + 2][e],  tile[ib + 3][e]);
    s0.z = pk2(tile[ib + 4][e],  tile[ib + 5][e]);
    s0.w = pk2(tile[ib + 6][e],  tile[ib + 7][e]);
    s1.x = pk2(tile[ib + 8][e],  tile[ib + 9][e]);
    s1.y = pk2(tile[ib + 10][e], tile[ib + 11][e]);
    s1.z = pk2(tile[ib + 12][e], tile[ib + 13][e]);
    s1.w = pk2(tile[ib + 14][e], tile[ib + 15][e]);
    ushort* dst = Xbf + ((size_t)(e * BT) + bt) * Vdim + i0 + ib;
    *(uint4*)dst = s0;
    *(uint4*)(dst + 8) = s1;
}

// ---------------------------------------------------------------------------
// K1b: Se[e][v][g] (bf16) = srpe[v][g][e] (f32)
// ---------------------------------------------------------------------------
__global__ __launch_bounds__(256) void k_se(const float* __restrict__ srpe,
                                            ushort* __restrict__ Se) {
    __shared__ float t2[256][65];        // [vv*32+g][e], pad 65
    const int tid = threadIdx.x;
    const int v0 = blockIdx.x * 8;
#pragma unroll
    for (int c = 0; c < 16; ++c) {
        int f = (c * 256 + tid) * 4;     // flat f32 idx within block slab
        int vg = f >> 6;
        int e4 = f & 63;
        *(float4*)&t2[vg][e4] = *(const float4*)(srpe + (size_t)v0 * Gdim * Edim + f);
    }
    __syncthreads();
    const int e = tid & 63;
#pragma unroll
    for (int h = 0; h < 2; ++h) {
        const int vv = (tid >> 6) * 2 + h;
        uint4 o[2];
#pragma unroll
        for (int c = 0; c < 2; ++c) {
            o[c].x = pk2(t2[vv * 32 + c * 16 + 0][e],  t2[vv * 32 + c * 16 + 1][e]);
            o[c].y = pk2(t2[vv * 32 + c * 16 + 2][e],  t2[vv * 32 + c * 16 + 3][e]);
            o[c].z = pk2(t2[vv * 32 + c * 16 + 4][e],  t2[vv * 32 + c * 16 + 5][e]);
            o[c].w = pk2(t2[vv * 32 + c * 16 + 6][e],  t2[vv * 32 + c * 16 + 7][e]);
        }
        uint4 o2[2];
#pragma unroll
        for (int c = 0; c < 2; ++c) {
            o2[c].x = pk2(t2[vv * 32 + c * 16 + 8][e],  t2[vv * 32 + c * 16 + 9][e]);
            o2[c].y = pk2(t2[vv * 32 + c * 16 + 10][e], t2[vv * 32 + c * 16 + 11][e]);
            o2[c].z = pk2(t2[vv * 32 + c * 16 + 12][e], t2[vv * 32 + c * 16 + 13][e]);
            o2[c].w = pk2(t2[vv * 32 + c * 16 + 14][e], t2[vv * 32 + c * 16 + 15][e]);
        }
        ushort* dst = Se + ((size_t)(e * Vdim) + v0 + vv) * Gdim;
        *(uint4*)(dst + 0)  = o[0];
        *(uint4*)(dst + 8)  = o2[0];
        *(uint4*)(dst + 16) = o[1];
        *(uint4*)(dst + 24) = o2[1];
    }
}

// ---------------------------------------------------------------------------
// K2: MFMA graph-mix, depth-2 counted-vmcnt pipeline (T3+T4), 1 barrier/step.
// Per wg: fixed e, 192 bt x 128 v, K over i (step 32, A/Si triple-buffered,
// R computed one step ahead, double-buffered). Sv in registers.
// Output: xrel bf16 [e][bt][v] into d_ws.
// ---------------------------------------------------------------------------
__global__ __launch_bounds__(256, 2) void k_relmix_mfma(const ushort* __restrict__ Xbf,
                                                        const ushort* __restrict__ Se,
                                                        ushort* __restrict__ xrel) {
    __shared__ __align__(16) ushort A_s[3][192 * 32];   // [bt][i], src-swizzled
    __shared__ __align__(16) ushort Si_s[3][32 * 32];   // [i][g],  src-swizzled
    __shared__ __align__(16) ushort R_s[2][128 * 40];   // [v][i],  80 B pitch

    const int tid = threadIdx.x;
    const int l = tid & 63;
    const int w = tid >> 6;              // wave 0..3
    const int wm = w >> 1;               // bt half (96 each)
    const int wn = w & 1;                // v half (64 each)

    // XCD-chunked swizzle: 128 consecutive wg (8 e values) per XCD.
    const int raw = blockIdx.x;                       // 0..1023
    const int wg  = (raw & 7) * 128 + (raw >> 3);     // bijective
    const int e   = wg >> 4;
    const int btT = (wg >> 3) & 1;
    const int vT  = wg & 7;
    const int bt0 = btT * 192;
    const int v0  = vT * 128;

    const int lr  = l >> 2;                           // sub-row in 16-row chunk
    const int lc  = ((l & 3) ^ (lr & 3)) * 8;         // swizzled col (ushort)

    const ushort* gA  = Xbf + ((size_t)(e * BT + bt0)) * Vdim;
    const ushort* gSi = Se + (size_t)e * Vdim * Gdim;

    // ---- Sv fragments: direct global -> regs (coalesced 1 KB per (w,k))
    bf16x8 svF[2];
    {
        const ushort* gSv = Se + ((size_t)e * Vdim + v0) * Gdim;
#pragma unroll
        for (int k = 0; k < 2; ++k) {
            const int vloc = (2 * w + k) * 16 + (l & 15);
            svF[k] = *(const bf16x8*)(gSv + (size_t)vloc * Gdim + (l >> 4) * 8);
        }
    }
    __builtin_amdgcn_sched_barrier(0);   // pin svF loads before the lds-loads

    // ---- prologue: issue Si0,A0,Si1,A1 (Si before A each step!)
    if (w < 2)
        __builtin_amdgcn_global_load_lds(gSi + (size_t)(0 + w * 16 + lr) * Gdim + lc,
                                         &Si_s[0][w * 512], 16, 0, 0);
#pragma unroll
    for (int c = 0; c < 3; ++c) {
        int chunk = w * 3 + c;
        __builtin_amdgcn_global_load_lds(gA + (size_t)(chunk * 16 + lr) * Vdim + 0 + lc,
                                         &A_s[0][chunk * 512], 16, 0, 0);
    }
    if (w < 2)
        __builtin_amdgcn_global_load_lds(gSi + (size_t)(32 + w * 16 + lr) * Gdim + lc,
                                         &Si_s[1][w * 512], 16, 0, 0);
#pragma unroll
    for (int c = 0; c < 3; ++c) {
        int chunk = w * 3 + c;
        __builtin_amdgcn_global_load_lds(gA + (size_t)(chunk * 16 + lr) * Vdim + 32 + lc,
                                         &A_s[1][chunk * 512], 16, 0, 0);
    }
    // wait: leave only newest A tile in flight -> Si0,A0,Si1 (and svF) landed
    asm volatile("s_waitcnt vmcnt(3)" ::: "memory");
    __builtin_amdgcn_sched_barrier(0);
    __builtin_amdgcn_s_barrier();
    __builtin_amdgcn_sched_barrier(0);

    const f32x4 fz = {0.f, 0.f, 0.f, 0.f};

    // ---- relation-tile compute: R[rb] = relu(Si[sb] . Sv^T)
    auto computeR = [&](int sb, int rb) {
        const int r0 = (l & 15), r1 = 16 + (l & 15);
        const int kg = l >> 4;
        bf16x8 siF0 = *(const bf16x8*)&Si_s[sb][r0 * 32 + (kg ^ (r0 & 3)) * 8];
        bf16x8 siF1 = *(const bf16x8*)&Si_s[sb][r1 * 32 + (kg ^ (r1 & 3)) * 8];
#pragma unroll
        for (int k = 0; k < 2; ++k) {
            const int vloc = (2 * w + k) * 16 + (l & 15);
            f32x4 d0 = __builtin_amdgcn_mfma_f32_16x16x32_bf16(siF0, svF[k], fz, 0, 0, 0);
            f32x4 d1 = __builtin_amdgcn_mfma_f32_16x16x32_bf16(siF1, svF[k], fz, 0, 0, 0);
            uint2 w0, w1;
            w0.x = pk2(fmaxf(d0[0], 0.f), fmaxf(d0[1], 0.f));
            w0.y = pk2(fmaxf(d0[2], 0.f), fmaxf(d0[3], 0.f));
            w1.x = pk2(fmaxf(d1[0], 0.f), fmaxf(d1[1], 0.f));
            w1.y = pk2(fmaxf(d1[2], 0.f), fmaxf(d1[3], 0.f));
            *(uint2*)&R_s[rb][vloc * 40 + kg * 4]      = w0;
            *(uint2*)&R_s[rb][vloc * 40 + 16 + kg * 4] = w1;
        }
    };

    // prologue R[0]
    computeR(0, 0);
    asm volatile("s_waitcnt lgkmcnt(0)" ::: "memory");
    __builtin_amdgcn_sched_barrier(0);
    __builtin_amdgcn_s_barrier();
    __builtin_amdgcn_sched_barrier(0);

    f32x4 acc[6][4];
#pragma unroll
    for (int m = 0; m < 6; ++m)
#pragma unroll
        for (int n = 0; n < 4; ++n) acc[m][n] = fz;

    int c0 = 0, c1 = 1, c2 = 2;          // A/Si buffers: cur, next, future
    int rc = 0, rn = 1;                  // R buffers: cur, next

    for (int t = 0; t < 32; ++t) {
        // ---- issue future loads (Si first, then A: keeps vmcnt(3) semantics)
        const int i0f = ((t + 2) & 31) * 32;   // wraps at tail: valid, never read
        if (w < 2)
            __builtin_amdgcn_global_load_lds(gSi + (size_t)(i0f + w * 16 + lr) * Gdim + lc,
                                             &Si_s[c2][w * 512], 16, 0, 0);
#pragma unroll
        for (int c = 0; c < 3; ++c) {
            int chunk = w * 3 + c;
            __builtin_amdgcn_global_load_lds(gA + (size_t)(chunk * 16 + lr) * Vdim + i0f + lc,
                                             &A_s[c2][chunk * 512], 16, 0, 0);
        }
        // ---- R[t+1] from Si[c1] (landed at end of prior step)
        computeR(c1, rn);
        // ---- A fragments (swizzled reads of current buffer)
        bf16x8 aF[6];
#pragma unroll
        for (int m = 0; m < 6; ++m) {
            const int row = wm * 96 + m * 16 + (l & 15);
            aF[m] = *(const bf16x8*)&A_s[c0][row * 32 + (((l >> 4) ^ (row & 3))) * 8];
        }
        // ---- 24 main MFMAs reading R[rc]
        __builtin_amdgcn_s_setprio(1);
#pragma unroll
        for (int n = 0; n < 4; ++n) {
            bf16x8 bF = *(const bf16x8*)&R_s[rc][(wn * 64 + n * 16 + (l & 15)) * 40 + (l >> 4) * 8];
#pragma unroll
            for (int m = 0; m < 6; ++m)
                acc[m][n] = __builtin_amdgcn_mfma_f32_16x16x32_bf16(aF[m], bF, acc[m][n], 0, 0, 0);
        }
        __builtin_amdgcn_s_setprio(0);
        // ---- single barrier: A[t+1]+Si[t+2] landed (vmcnt(3)), LDS ops drained
        asm volatile("s_waitcnt vmcnt(3) lgkmcnt(0)" ::: "memory");
        __builtin_amdgcn_sched_barrier(0);
        __builtin_amdgcn_s_barrier();
        __builtin_amdgcn_sched_barrier(0);
        // ---- rotate buffers
        int tmp = c0; c0 = c1; c1 = c2; c2 = tmp;
        tmp = rc; rc = rn; rn = tmp;
    }

    // ---- epilogue: bf16 stores, v-contiguous across lanes (32 B runs)
#pragma unroll
    for (int m = 0; m < 6; ++m) {
        const int btl = bt0 + wm * 96 + m * 16 + (l >> 4) * 4;
#pragma unroll
        for (int j = 0; j < 4; ++j) {
            ushort* row = xrel + ((size_t)(e * BT) + btl + j) * Vdim + v0;
#pragma unroll
            for (int n = 0; n < 4; ++n)
                row[wn * 64 + n * 16 + (l & 15)] = f2bf(acc[m][n][j]);
        }
    }
}

// ---------------------------------------------------------------------------
// K3: per (t,v): y[b,e] = leaky( sum_f xl[b,f] * W[t,v,f,e] + bias )
// No W LDS staging: wave w owns e-block [16w,16w+16); B-fragments loaded
// direct global->reg (64 B coalesced segments), packed bf16 in-register.
// x_rel gathered straight from xrel[e][bt][v] (L3-resident, no xrT pass).
// ---------------------------------------------------------------------------
__global__ __launch_bounds__(256, 4) void k_final(const ushort* __restrict__ xrel,
        const int* __restrict__ n_route, const int* __restrict__ s_week,
        const int* __restrict__ s_day,  const float* __restrict__ sape,
        const float* __restrict__ dow,  const float* __restrict__ tod,
        const float* __restrict__ Wc,   const float* __restrict__ bias,
        float* __restrict__ out) {
    __shared__ __align__(16) ushort xs[32 * 208];   // xl bf16 [b][f], pitch 208
    __shared__ float bl[64];
    const int tid = threadIdx.x;
    const int l = tid & 63, w = tid >> 6;
    const int v  = blockIdx.x & (Vdim - 1);
    const int tt = blockIdx.x >> 10;

    // ---- build xl bf16 [b][f]: [x_rel gather | sape | dow+tod]
    {
        const int b  = tid >> 3;
        const int e0 = (tid & 7) * 8;
        const int bt = b * Tdim + tt;
        ushort tmp[8];
#pragma unroll
        for (int k = 0; k < 8; ++k)
            tmp[k] = xrel[((size_t)((e0 + k) * BT) + bt) * Vdim + v];
        uint4 o0;
        o0.x = (uint)tmp[0] | ((uint)tmp[1] << 16);
        o0.y = (uint)tmp[2] | ((uint)tmp[3] << 16);
        o0.z = (uint)tmp[4] | ((uint)tmp[5] << 16);
        o0.w = (uint)tmp[6] | ((uint)tmp[7] << 16);
        *(uint4*)&xs[b * 208 + e0] = o0;
        const int r  = n_route[b * Vdim + v];
        const float* sp = sape + ((size_t)(r * Tdim) + tt) * Edim + e0;
        const int wd = s_week[bt], dd = s_day[bt];
        const float* dp = dow + ((size_t)(wd * Vdim) + v) * Edim + e0;
        const float* tp = tod + ((size_t)(dd * Vdim) + v) * Edim + e0;
        uint4 o1, o2;
        o1.x = pk2(sp[0], sp[1]); o1.y = pk2(sp[2], sp[3]);
        o1.z = pk2(sp[4], sp[5]); o1.w = pk2(sp[6], sp[7]);
        *(uint4*)&xs[b * 208 + 64 + e0] = o1;
        o2.x = pk2(dp[0] + tp[0], dp[1] + tp[1]);
        o2.y = pk2(dp[2] + tp[2], dp[3] + tp[3]);
        o2.z = pk2(dp[4] + tp[4], dp[5] + tp[5]);
        o2.w = pk2(dp[6] + tp[6], dp[7] + tp[7]);
        *(uint4*)&xs[b * 208 + 128 + e0] = o2;
    }
    if (tid < 64) bl[tid] = bias[((size_t)(tt * Vdim) + v) * Edim + tid];

    // ---- W fragment loads: direct to regs (independent of barrier)
    const int ecol = w * 16 + (l & 15);
    const int fb   = (l >> 4) * 8;       // k-chunk base within 32
    const float* Wg = Wc + ((size_t)(tt * Vdim + v)) * 192 * Edim + ecol;
    float wv[48];
#pragma unroll
    for (int ks = 0; ks < 6; ++ks)
#pragma unroll
        for (int j = 0; j < 8; ++j)
            wv[ks * 8 + j] = Wg[(size_t)(ks * 32 + fb + j) * Edim];

    __syncthreads();

    // ---- 12 MFMAs: D[b][e], A = xs rows b, B = W cols e
    const f32x4 fz = {0.f, 0.f, 0.f, 0.f};
    f32x4 acc[2] = {fz, fz};
#pragma unroll
    for (int ks = 0; ks < 6; ++ks) {
        uint4 uu;
        uu.x = pk2(wv[ks * 8 + 0], wv[ks * 8 + 1]);
        uu.y = pk2(wv[ks * 8 + 2], wv[ks * 8 + 3]);
        uu.z = pk2(wv[ks * 8 + 4], wv[ks * 8 + 5]);
        uu.w = pk2(wv[ks * 8 + 6], wv[ks * 8 + 7]);
        bf16x8 bF;
        __builtin_memcpy(&bF, &uu, 16);
#pragma unroll
        for (int mt = 0; mt < 2; ++mt) {
            bf16x8 aF = *(const bf16x8*)&xs[(mt * 16 + (l & 15)) * 208 + ks * 32 + fb];
            acc[mt] = __builtin_amdgcn_mfma_f32_16x16x32_bf16(aF, bF, acc[mt], 0, 0, 0);
        }
    }
    // ---- epilogue: bias + leaky, 64 B runs per 16 lanes
    const float bv = bl[ecol];
#pragma unroll
    for (int mt = 0; mt < 2; ++mt) {
        const int b0r = mt * 16 + (l >> 4) * 4;
#pragma unroll
        for (int j = 0; j < 4; ++j) {
            float s = acc[mt][j] + bv;
            s = s > 0.f ? s : 0.3f * s;
            out[((size_t)((b0r + j) * Tdim + tt) * Vdim + v) * Edim + ecol] = s;
        }
    }
}

// ---------------------------------------------------------------------------
extern "C" void kernel_launch(void* const* d_in, const int* in_sizes, int n_in,
                              void* d_out, int out_size, void* d_ws, size_t ws_size,
                              hipStream_t stream) {
    const float* inputs = (const float*)d_in[0];
    const int*   n_route= (const int*)d_in[1];
    const int*   s_week = (const int*)d_in[2];
    const int*   s_day  = (const int*)d_in[3];
    const float* srpe   = (const float*)d_in[4];
    const float* sape   = (const float*)d_in[5];
    const float* dow    = (const float*)d_in[6];
    const float* tod    = (const float*)d_in[7];
    const float* Wc     = (const float*)d_in[8];
    const float* bias   = (const float*)d_in[9];

    // ws layout: Xbf [0,48MB) ; Se [48MB,52MB) ; xrel [64MB,112MB)
    ushort* Xbf  = (ushort*)d_ws;
    ushort* Se   = (ushort*)((char*)d_ws + (size_t)Edim * BT * Vdim * 2);
    ushort* xrel = (ushort*)((char*)d_ws + (size_t)64 * 1024 * 1024);
    float*  out  = (float*)d_out;

    k_xpose<<<dim3(BT * 16), dim3(256), 0, stream>>>(inputs, Xbf);
    k_se<<<dim3(Vdim / 8), dim3(256), 0, stream>>>(srpe, Se);
    k_relmix_mfma<<<dim3(1024), dim3(256), 0, stream>>>(Xbf, Se, xrel);
    k_final<<<dim3(Tdim * Vdim), dim3(256), 0, stream>>>(
        xrel, n_route, s_week, s_day, sape, dow, tod, Wc, bias, out);
}